// Round 2
// baseline (3448.960 us; speedup 1.0000x reference)
//
#include <hip/hip_runtime.h>
#include <cstdint>
#include <cstddef>

#define NBATCH  8
#define NPTS    8192
#define NFEAT   64
#define NPOINT  2048
#define NSAMPLE 32

// ---------------------------------------------------------------------------
// prep: fold BN into weights (y = dot*s + t), transpose to [c][o]
// wbuf float layout:
//  [0,4288)      wT1[c=67][o=64] = w1[o][c]*s1[o]
//  [4288,4352)   t1[o]
//  [4352,8448)   wT2[c=64][o=64]
//  [8448,8512)   t2[o]
//  [8512,16704)  wT3[c=64][o=128]
//  [16704,16832) t3[o]
// ---------------------------------------------------------------------------
__global__ void prep_kernel(const float* __restrict__ w1, const float* __restrict__ b1,
                            const float* __restrict__ g1, const float* __restrict__ bb1,
                            const float* __restrict__ m1, const float* __restrict__ v1,
                            const float* __restrict__ w2, const float* __restrict__ b2,
                            const float* __restrict__ g2, const float* __restrict__ bb2,
                            const float* __restrict__ m2, const float* __restrict__ v2,
                            const float* __restrict__ w3, const float* __restrict__ b3,
                            const float* __restrict__ g3, const float* __restrict__ bb3,
                            const float* __restrict__ m3, const float* __restrict__ v3,
                            float* __restrict__ wbuf) {
    int i = blockIdx.x * 256 + threadIdx.x;
    if (i < 4288) {
        int o = i & 63, c = i >> 6;
        float s = g1[o] / sqrtf(v1[o] + 1e-5f);
        wbuf[i] = w1[o * 67 + c] * s;
    } else if (i < 4352) {
        int o = i - 4288;
        float s = g1[o] / sqrtf(v1[o] + 1e-5f);
        wbuf[i] = (b1[o] - m1[o]) * s + bb1[o];
    } else if (i < 8448) {
        int j = i - 4352; int o = j & 63, c = j >> 6;
        float s = g2[o] / sqrtf(v2[o] + 1e-5f);
        wbuf[i] = w2[o * 64 + c] * s;
    } else if (i < 8512) {
        int o = i - 8448;
        float s = g2[o] / sqrtf(v2[o] + 1e-5f);
        wbuf[i] = (b2[o] - m2[o]) * s + bb2[o];
    } else if (i < 16704) {
        int j = i - 8512; int o = j & 127, c = j >> 7;
        float s = g3[o] / sqrtf(v3[o] + 1e-5f);
        wbuf[i] = w3[o * 64 + c] * s;
    } else if (i < 16832) {
        int o = i - 16704;
        float s = g3[o] / sqrtf(v3[o] + 1e-5f);
        wbuf[i] = (b3[o] - m3[o]) * s + bb3[o];
    }
}

// ---------------------------------------------------------------------------
// FPS: one block per batch, 512 threads, 16 points/thread in registers.
// Exact IEEE f32, no FMA contraction (matches np elementwise-square + ascending
// pairwise sum). Argmax ties -> smallest index (numpy).
// ---------------------------------------------------------------------------
__global__ __launch_bounds__(512) void fps_kernel(const float* __restrict__ points,
                                                  int* __restrict__ fidx) {
    const int b = blockIdx.x;
    const int tid = threadIdx.x;
    const int lane = tid & 63;
    const float* __restrict__ pxg = points + (size_t)b * 3 * NPTS;
    const float* __restrict__ pyg = pxg + NPTS;
    const float* __restrict__ pzg = pyg + NPTS;

    float px[16], py[16], pz[16], dd[16];
#pragma unroll
    for (int j = 0; j < 16; ++j) {
        int n = tid + 512 * j;
        px[j] = pxg[n]; py[j] = pyg[n]; pz[j] = pzg[n];
        dd[j] = 1e10f;
    }
    __shared__ float pv[2][8];
    __shared__ int   pi[2][8];
    if (tid == 0) fidx[b * NPOINT + 0] = 0;
    int w = 0;
    for (int i = 1; i < NPOINT; ++i) {
        // broadcast load of current centroid (same address in every lane)
        const float cx = pxg[w], cy = pyg[w], cz = pzg[w];
        float bestd = -1.0f; int besti = 0;
#pragma unroll
        for (int j = 0; j < 16; ++j) {
            float dx = __fsub_rn(px[j], cx);
            float dy = __fsub_rn(py[j], cy);
            float dz = __fsub_rn(pz[j], cz);
            float d  = __fadd_rn(__fadd_rn(__fmul_rn(dx, dx), __fmul_rn(dy, dy)),
                                 __fmul_rn(dz, dz));
            float nd = fminf(dd[j], d);
            dd[j] = nd;
            bool better = (nd > bestd);   // strict > keeps smaller idx on tie
            bestd = better ? nd : bestd;
            besti = better ? (tid + 512 * j) : besti;
        }
        // wave-level argmax reduce (max dist, tie -> min idx)
#pragma unroll
        for (int off = 32; off >= 1; off >>= 1) {
            float od = __shfl_down(bestd, off);
            int   oi = __shfl_down(besti, off);
            bool take = (od > bestd) || (od == bestd && oi < besti);
            bestd = take ? od : bestd;
            besti = take ? oi : besti;
        }
        const int par = i & 1;  // double-buffered partials -> single barrier/iter
        if (lane == 0) { pv[par][tid >> 6] = bestd; pi[par][tid >> 6] = besti; }
        __syncthreads();
        // every wave redundantly reduces the 8 partials (no broadcast barrier)
        float fd = (lane < 8) ? pv[par][lane] : -1.0f;
        int   fi = (lane < 8) ? pi[par][lane] : 0x7fffffff;
#pragma unroll
        for (int off = 4; off >= 1; off >>= 1) {
            float od = __shfl_down(fd, off);
            int   oi = __shfl_down(fi, off);
            bool take = (od > fd) || (od == fd && oi < fi);
            fd = take ? od : fd;
            fi = take ? oi : fi;
        }
        w = __shfl(fi, 0);
        if (tid == 0) fidx[b * NPOINT + i] = w;
    }
}

// ---------------------------------------------------------------------------
// Ball query: one wave per query. d = (qq+pp) - 2*qp, compare vs 0.04f.
// qp is the K=3 einsum/dot -> BLAS/XLA-style ASCENDING FMA chain:
//   qp = fma(qz,z, fma(qy,y, qx*x))          <-- changed this round
// qq/pp are elementwise-square + ascending rounded sums (matches np.sum,
// evidenced by FPS matching exactly with the same recipe).
// ---------------------------------------------------------------------------
__global__ __launch_bounds__(256) void bq_kernel(const float* __restrict__ points,
                                                 const int* __restrict__ fidx,
                                                 int* __restrict__ ballidx,
                                                 float* __restrict__ out_xyz) {
    const int lane = threadIdx.x & 63;
    const int gw = (blockIdx.x << 2) + (threadIdx.x >> 6);
    const int b = gw >> 11;
    const int q = gw & 2047;
    const float* __restrict__ pxg = points + (size_t)b * 3 * NPTS;
    const float* __restrict__ pyg = pxg + NPTS;
    const float* __restrict__ pzg = pyg + NPTS;
    const int qi = fidx[b * NPOINT + q];
    const float qx = pxg[qi], qy = pyg[qi], qz = pzg[qi];
    const float qq = __fadd_rn(__fadd_rn(__fmul_rn(qx, qx), __fmul_rn(qy, qy)),
                               __fmul_rn(qz, qz));
    int* __restrict__ out = ballidx + ((size_t)(b * NPOINT + q)) * NSAMPLE;
    int have = 0;
    int first = -1;
    for (int base = 0; base < NPTS && have < NSAMPLE; base += 64) {
        const int n = base + lane;
        float x = pxg[n], y = pyg[n], z = pzg[n];
        float pp = __fadd_rn(__fadd_rn(__fmul_rn(x, x), __fmul_rn(y, y)), __fmul_rn(z, z));
        float qp = __builtin_fmaf(qz, z, __builtin_fmaf(qy, y, __fmul_rn(qx, x)));
        float d  = __fsub_rn(__fadd_rn(qq, pp), __fmul_rn(2.0f, qp));
        bool inb = d < 0.04f;   // f32(0.2*0.2) == 0.04f (same verdict as f64 cmp)
        unsigned long long mask = __ballot(inb);
        if (mask) {
            if (first < 0) first = base + __ffsll(mask) - 1;
            if (inb) {
                int slot = have + (int)__popcll(mask & ((1ull << lane) - 1ull));
                if (slot < NSAMPLE) out[slot] = n;
            }
            have += (int)__popcll(mask);
        }
    }
    for (int s = have + lane; s < NSAMPLE; s += 64) out[s] = first;
    if (lane == 0) {
        float* o0 = out_xyz + (size_t)b * 3 * NPOINT + q;
        o0[0] = qx; o0[NPOINT] = qy; o0[2 * NPOINT] = qz;
    }
}

// ---------------------------------------------------------------------------
// Fused gather + 3-layer MLP (BN folded) + max-pool. One query per block,
// 256 threads. LDS tiles with stride 36 (float4-aligned, writes only 8-way).
// ---------------------------------------------------------------------------
#define XS 36
__global__ __launch_bounds__(256) void mlp_kernel(const float* __restrict__ feats,
                                                  const float* __restrict__ points,
                                                  const int* __restrict__ fidx,
                                                  const int* __restrict__ ballidx,
                                                  const float* __restrict__ wbuf,
                                                  float* __restrict__ out) {
    __shared__ float xT[67 * XS];   // [c][k], also reused for y2
    __shared__ float yA[64 * XS];   // y1, also reused for final partial max
    __shared__ float wl[8192];      // current layer's folded weights [c][o]
    __shared__ float bl[128];
    __shared__ int   il[32];
    __shared__ float qv[3];
    const int tid = threadIdx.x;
    const int bq = blockIdx.x;
    const int b = bq >> 11, q = bq & 2047;
    const float* __restrict__ pb = points + (size_t)b * 3 * NPTS;

    if (tid < 32) il[tid] = ballidx[((size_t)(b * NPOINT + q)) * NSAMPLE + tid];
    if (tid < 3)  qv[tid] = pb[(size_t)tid * NPTS + fidx[b * NPOINT + q]];
    for (int i = tid; i < 4288; i += 256) wl[i] = wbuf[i];
    if (tid < 64) bl[tid] = wbuf[4288 + tid];
    __syncthreads();

    // build xT: rows 0..2 = grouped_xyz, rows 3..66 = gathered features
    if (tid < 32) {
        int n = il[tid];
        xT[0 * XS + tid] = pb[n] - qv[0];
        xT[1 * XS + tid] = pb[NPTS + n] - qv[1];
        xT[2 * XS + tid] = pb[2 * NPTS + n] - qv[2];
    }
    {
        int k = tid & 31, fg = tid >> 5;
        int n = il[k];
        const float* fb = feats + ((size_t)b * NFEAT + fg * 8) * NPTS + n;
#pragma unroll
        for (int u = 0; u < 8; ++u) xT[(3 + fg * 8 + u) * XS + k] = fb[(size_t)u * NPTS];
    }
    __syncthreads();

    const int o = tid & 63, kb = tid >> 6;
    float acc[8];
    // ---- layer 1: 67 -> 64 ----
#pragma unroll
    for (int j = 0; j < 8; ++j) acc[j] = 0.f;
    for (int c = 0; c < 67; ++c) {
        float wv = wl[c * 64 + o];
        const float4* xp = (const float4*)&xT[c * XS + kb * 8];
        float4 a0 = xp[0], a1 = xp[1];
        acc[0] = fmaf(wv, a0.x, acc[0]); acc[1] = fmaf(wv, a0.y, acc[1]);
        acc[2] = fmaf(wv, a0.z, acc[2]); acc[3] = fmaf(wv, a0.w, acc[3]);
        acc[4] = fmaf(wv, a1.x, acc[4]); acc[5] = fmaf(wv, a1.y, acc[5]);
        acc[6] = fmaf(wv, a1.z, acc[6]); acc[7] = fmaf(wv, a1.w, acc[7]);
    }
    {
        float t = bl[o];
#pragma unroll
        for (int j = 0; j < 8; ++j) {
            float y = acc[j] + t;
            y = y > 0.f ? y : 0.2f * y;
            yA[o * XS + kb * 8 + j] = y;
        }
    }
    __syncthreads();
    for (int i = tid; i < 4096; i += 256) wl[i] = wbuf[4352 + i];
    if (tid < 64) bl[tid] = wbuf[8448 + tid];
    __syncthreads();

    // ---- layer 2: 64 -> 64 ----
#pragma unroll
    for (int j = 0; j < 8; ++j) acc[j] = 0.f;
    for (int c = 0; c < 64; ++c) {
        float wv = wl[c * 64 + o];
        const float4* xp = (const float4*)&yA[c * XS + kb * 8];
        float4 a0 = xp[0], a1 = xp[1];
        acc[0] = fmaf(wv, a0.x, acc[0]); acc[1] = fmaf(wv, a0.y, acc[1]);
        acc[2] = fmaf(wv, a0.z, acc[2]); acc[3] = fmaf(wv, a0.w, acc[3]);
        acc[4] = fmaf(wv, a1.x, acc[4]); acc[5] = fmaf(wv, a1.y, acc[5]);
        acc[6] = fmaf(wv, a1.z, acc[6]); acc[7] = fmaf(wv, a1.w, acc[7]);
    }
    {
        float t = bl[o];
#pragma unroll
        for (int j = 0; j < 8; ++j) {
            float y = acc[j] + t;
            y = y > 0.f ? y : 0.2f * y;
            xT[o * XS + kb * 8 + j] = y;   // y2 into xT (xT reads all done)
        }
    }
    __syncthreads();
    for (int i = tid; i < 8192; i += 256) wl[i] = wbuf[8512 + i];
    if (tid < 128) bl[tid] = wbuf[16704 + tid];
    __syncthreads();

    // ---- layer 3: 64 -> 128, fused max over k ----
    const int o3 = tid & 127, kb3 = tid >> 7;
    float a3[16];
#pragma unroll
    for (int j = 0; j < 16; ++j) a3[j] = 0.f;
    for (int c = 0; c < 64; ++c) {
        float wv = wl[c * 128 + o3];
        const float4* xp = (const float4*)&xT[c * XS + kb3 * 16];
        float4 x0 = xp[0], x1 = xp[1], x2 = xp[2], x3 = xp[3];
        a3[0]  = fmaf(wv, x0.x, a3[0]);  a3[1]  = fmaf(wv, x0.y, a3[1]);
        a3[2]  = fmaf(wv, x0.z, a3[2]);  a3[3]  = fmaf(wv, x0.w, a3[3]);
        a3[4]  = fmaf(wv, x1.x, a3[4]);  a3[5]  = fmaf(wv, x1.y, a3[5]);
        a3[6]  = fmaf(wv, x1.z, a3[6]);  a3[7]  = fmaf(wv, x1.w, a3[7]);
        a3[8]  = fmaf(wv, x2.x, a3[8]);  a3[9]  = fmaf(wv, x2.y, a3[9]);
        a3[10] = fmaf(wv, x2.z, a3[10]); a3[11] = fmaf(wv, x2.w, a3[11]);
        a3[12] = fmaf(wv, x3.x, a3[12]); a3[13] = fmaf(wv, x3.y, a3[13]);
        a3[14] = fmaf(wv, x3.z, a3[14]); a3[15] = fmaf(wv, x3.w, a3[15]);
    }
    {
        float t = bl[o3];
        float m = -3.4e38f;
#pragma unroll
        for (int j = 0; j < 16; ++j) {
            float y = a3[j] + t;
            y = y > 0.f ? y : 0.2f * y;
            m = fmaxf(m, y);
        }
        yA[o3 * 2 + kb3] = m;
    }
    __syncthreads();
    if (tid < 128) {
        float r = fmaxf(yA[tid * 2], yA[tid * 2 + 1]);
        out[((size_t)b * 128 + tid) * NPOINT + q] = r;
    }
}

// ---------------------------------------------------------------------------
extern "C" void kernel_launch(void* const* d_in, const int* in_sizes, int n_in,
                              void* d_out, int out_size, void* d_ws, size_t ws_size,
                              hipStream_t stream) {
    (void)in_sizes; (void)n_in; (void)out_size; (void)ws_size;
    const float* feats  = (const float*)d_in[0];
    const float* points = (const float*)d_in[1];
    const float* w1  = (const float*)d_in[2];
    const float* b1  = (const float*)d_in[3];
    const float* g1  = (const float*)d_in[4];
    const float* bb1 = (const float*)d_in[5];
    const float* m1  = (const float*)d_in[6];
    const float* v1  = (const float*)d_in[7];
    const float* w2  = (const float*)d_in[8];
    const float* b2  = (const float*)d_in[9];
    const float* g2  = (const float*)d_in[10];
    const float* bb2 = (const float*)d_in[11];
    const float* m2  = (const float*)d_in[12];
    const float* v2  = (const float*)d_in[13];
    const float* w3  = (const float*)d_in[14];
    const float* b3  = (const float*)d_in[15];
    const float* g3  = (const float*)d_in[16];
    const float* bb3 = (const float*)d_in[17];
    const float* m3  = (const float*)d_in[18];
    const float* v3  = (const float*)d_in[19];

    float* out = (float*)d_out;
    char*  ws  = (char*)d_ws;
    int*   fidx    = (int*)ws;                           // 8*2048 int = 64 KB
    int*   ballidx = (int*)(ws + 65536);                 // 8*2048*32 int = 2 MB
    float* wbuf    = (float*)(ws + 65536 + 2097152);     // 16832 floats
    float* out_xyz = out + (size_t)NBATCH * 128 * NPOINT;

    hipLaunchKernelGGL(prep_kernel, dim3(66), dim3(256), 0, stream,
                       w1, b1, g1, bb1, m1, v1, w2, b2, g2, bb2, m2, v2,
                       w3, b3, g3, bb3, m3, v3, wbuf);
    hipLaunchKernelGGL(fps_kernel, dim3(NBATCH), dim3(512), 0, stream, points, fidx);
    hipLaunchKernelGGL(bq_kernel, dim3(16384 / 4), dim3(256), 0, stream,
                       points, fidx, ballidx, out_xyz);
    hipLaunchKernelGGL(mlp_kernel, dim3(NBATCH * NPOINT), dim3(256), 0, stream,
                       feats, points, fidx, ballidx, wbuf, out);
}

// Round 3
// 3262.033 us; speedup vs baseline: 1.0573x; 1.0573x over previous
//
#include <hip/hip_runtime.h>
#include <cstdint>
#include <cstddef>

#define NBATCH  8
#define NPTS    8192
#define NFEAT   64
#define NPOINT  2048
#define NSAMPLE 32

// ---------------------------------------------------------------------------
// prep: fold BN into weights (y = dot*s + t), transpose to [c][o]
// ---------------------------------------------------------------------------
__global__ void prep_kernel(const float* __restrict__ w1, const float* __restrict__ b1,
                            const float* __restrict__ g1, const float* __restrict__ bb1,
                            const float* __restrict__ m1, const float* __restrict__ v1,
                            const float* __restrict__ w2, const float* __restrict__ b2,
                            const float* __restrict__ g2, const float* __restrict__ bb2,
                            const float* __restrict__ m2, const float* __restrict__ v2,
                            const float* __restrict__ w3, const float* __restrict__ b3,
                            const float* __restrict__ g3, const float* __restrict__ bb3,
                            const float* __restrict__ m3, const float* __restrict__ v3,
                            float* __restrict__ wbuf) {
    int i = blockIdx.x * 256 + threadIdx.x;
    if (i < 4288) {
        int o = i & 63, c = i >> 6;
        float s = g1[o] / sqrtf(v1[o] + 1e-5f);
        wbuf[i] = w1[o * 67 + c] * s;
    } else if (i < 4352) {
        int o = i - 4288;
        float s = g1[o] / sqrtf(v1[o] + 1e-5f);
        wbuf[i] = (b1[o] - m1[o]) * s + bb1[o];
    } else if (i < 8448) {
        int j = i - 4352; int o = j & 63, c = j >> 6;
        float s = g2[o] / sqrtf(v2[o] + 1e-5f);
        wbuf[i] = w2[o * 64 + c] * s;
    } else if (i < 8512) {
        int o = i - 8448;
        float s = g2[o] / sqrtf(v2[o] + 1e-5f);
        wbuf[i] = (b2[o] - m2[o]) * s + bb2[o];
    } else if (i < 16704) {
        int j = i - 8512; int o = j & 127, c = j >> 7;
        float s = g3[o] / sqrtf(v3[o] + 1e-5f);
        wbuf[i] = w3[o * 64 + c] * s;
    } else if (i < 16832) {
        int o = i - 16704;
        float s = g3[o] / sqrtf(v3[o] + 1e-5f);
        wbuf[i] = (b3[o] - m3[o]) * s + bb3[o];
    }
}

// ---------------------------------------------------------------------------
// FPS: one block per batch, 512 threads, 16 points/thread in REGISTERS
// (launch_bounds(512,2) -> 256 VGPR/wave budget, no spill). Point cloud also
// staged to LDS so the serially-dependent centroid fetch is an LDS broadcast.
// Exact IEEE f32, no FMA contraction. Argmax ties -> smallest index (numpy).
// ---------------------------------------------------------------------------
__global__ __launch_bounds__(512, 2) void fps_kernel(const float* __restrict__ points,
                                                     int* __restrict__ fidx) {
    const int b = blockIdx.x;
    const int tid = threadIdx.x;
    const int lane = tid & 63;
    const float* __restrict__ pxg = points + (size_t)b * 3 * NPTS;
    const float* __restrict__ pyg = pxg + NPTS;
    const float* __restrict__ pzg = pyg + NPTS;

    __shared__ float lx[NPTS];     // 32 KB
    __shared__ float ly[NPTS];     // 32 KB
    __shared__ float lz[NPTS];     // 32 KB
    __shared__ float pv[2][8];
    __shared__ int   pi[2][8];

    float px[16], py[16], pz[16], dd[16];
#pragma unroll
    for (int j = 0; j < 16; ++j) {
        int n = tid + 512 * j;
        px[j] = pxg[n]; py[j] = pyg[n]; pz[j] = pzg[n];
        lx[n] = px[j];  ly[n] = py[j];  lz[n] = pz[j];
        dd[j] = 1e10f;
    }
    if (tid == 0) fidx[b * NPOINT + 0] = 0;
    __syncthreads();
    int w = 0;
    for (int i = 1; i < NPOINT; ++i) {
        // broadcast read of current centroid from LDS (same addr all lanes)
        const float cx = lx[w], cy = ly[w], cz = lz[w];
        float bestd = -1.0f; int besti = 0;
#pragma unroll
        for (int j = 0; j < 16; ++j) {
            float dx = __fsub_rn(px[j], cx);
            float dy = __fsub_rn(py[j], cy);
            float dz = __fsub_rn(pz[j], cz);
            float d  = __fadd_rn(__fadd_rn(__fmul_rn(dx, dx), __fmul_rn(dy, dy)),
                                 __fmul_rn(dz, dz));
            float nd = fminf(dd[j], d);
            dd[j] = nd;
            bool better = (nd > bestd);   // strict > keeps smaller idx on tie
            bestd = better ? nd : bestd;
            besti = better ? (tid + 512 * j) : besti;
        }
        // wave-level argmax reduce (max dist, tie -> min idx)
#pragma unroll
        for (int off = 32; off >= 1; off >>= 1) {
            float od = __shfl_down(bestd, off);
            int   oi = __shfl_down(besti, off);
            bool take = (od > bestd) || (od == bestd && oi < besti);
            bestd = take ? od : bestd;
            besti = take ? oi : besti;
        }
        const int par = i & 1;  // double-buffered partials -> single barrier/iter
        if (lane == 0) { pv[par][tid >> 6] = bestd; pi[par][tid >> 6] = besti; }
        __syncthreads();
        // every wave redundantly reduces the 8 partials (no broadcast barrier)
        float fd = (lane < 8) ? pv[par][lane] : -1.0f;
        int   fi = (lane < 8) ? pi[par][lane] : 0x7fffffff;
#pragma unroll
        for (int off = 4; off >= 1; off >>= 1) {
            float od = __shfl_down(fd, off);
            int   oi = __shfl_down(fi, off);
            bool take = (od > fd) || (od == fd && oi < fi);
            fd = take ? od : fd;
            fi = take ? oi : fi;
        }
        w = __shfl(fi, 0);
        if (tid == 0) fidx[b * NPOINT + i] = w;
    }
}

// ---------------------------------------------------------------------------
// Ball query: one wave per query. d = (qq+pp) - 2*qp, compare vs 0.04f.
// qp is the K=3 einsum/dot -> ascending FMA chain (verified exact in R1).
// ---------------------------------------------------------------------------
__global__ __launch_bounds__(256) void bq_kernel(const float* __restrict__ points,
                                                 const int* __restrict__ fidx,
                                                 int* __restrict__ ballidx,
                                                 float* __restrict__ out_xyz) {
    const int lane = threadIdx.x & 63;
    const int gw = (blockIdx.x << 2) + (threadIdx.x >> 6);
    const int b = gw >> 11;
    const int q = gw & 2047;
    const float* __restrict__ pxg = points + (size_t)b * 3 * NPTS;
    const float* __restrict__ pyg = pxg + NPTS;
    const float* __restrict__ pzg = pyg + NPTS;
    const int qi = fidx[b * NPOINT + q];
    const float qx = pxg[qi], qy = pyg[qi], qz = pzg[qi];
    const float qq = __fadd_rn(__fadd_rn(__fmul_rn(qx, qx), __fmul_rn(qy, qy)),
                               __fmul_rn(qz, qz));
    int* __restrict__ out = ballidx + ((size_t)(b * NPOINT + q)) * NSAMPLE;
    int have = 0;
    int first = -1;
    for (int base = 0; base < NPTS && have < NSAMPLE; base += 64) {
        const int n = base + lane;
        float x = pxg[n], y = pyg[n], z = pzg[n];
        float pp = __fadd_rn(__fadd_rn(__fmul_rn(x, x), __fmul_rn(y, y)), __fmul_rn(z, z));
        float qp = __builtin_fmaf(qz, z, __builtin_fmaf(qy, y, __fmul_rn(qx, x)));
        float d  = __fsub_rn(__fadd_rn(qq, pp), __fmul_rn(2.0f, qp));
        bool inb = d < 0.04f;   // f32(0.2*0.2) == 0.04f
        unsigned long long mask = __ballot(inb);
        if (mask) {
            if (first < 0) first = base + __ffsll(mask) - 1;
            if (inb) {
                int slot = have + (int)__popcll(mask & ((1ull << lane) - 1ull));
                if (slot < NSAMPLE) out[slot] = n;
            }
            have += (int)__popcll(mask);
        }
    }
    for (int s = have + lane; s < NSAMPLE; s += 64) out[s] = first;
    if (lane == 0) {
        float* o0 = out_xyz + (size_t)b * 3 * NPOINT + q;
        o0[0] = qx; o0[NPOINT] = qy; o0[2 * NPOINT] = qz;
    }
}

// ---------------------------------------------------------------------------
// Fused gather + 3-layer MLP (BN folded) + max-pool. One query per block,
// 256 threads. LDS tiles with stride 36 (float4-aligned, writes only 8-way).
// ---------------------------------------------------------------------------
#define XS 36
__global__ __launch_bounds__(256) void mlp_kernel(const float* __restrict__ feats,
                                                  const float* __restrict__ points,
                                                  const int* __restrict__ fidx,
                                                  const int* __restrict__ ballidx,
                                                  const float* __restrict__ wbuf,
                                                  float* __restrict__ out) {
    __shared__ float xT[67 * XS];   // [c][k], also reused for y2
    __shared__ float yA[64 * XS];   // y1, also reused for final partial max
    __shared__ float wl[8192];      // current layer's folded weights [c][o]
    __shared__ float bl[128];
    __shared__ int   il[32];
    __shared__ float qv[3];
    const int tid = threadIdx.x;
    const int bq = blockIdx.x;
    const int b = bq >> 11, q = bq & 2047;
    const float* __restrict__ pb = points + (size_t)b * 3 * NPTS;

    if (tid < 32) il[tid] = ballidx[((size_t)(b * NPOINT + q)) * NSAMPLE + tid];
    if (tid < 3)  qv[tid] = pb[(size_t)tid * NPTS + fidx[b * NPOINT + q]];
    for (int i = tid; i < 4288; i += 256) wl[i] = wbuf[i];
    if (tid < 64) bl[tid] = wbuf[4288 + tid];
    __syncthreads();

    // build xT: rows 0..2 = grouped_xyz, rows 3..66 = gathered features
    if (tid < 32) {
        int n = il[tid];
        xT[0 * XS + tid] = pb[n] - qv[0];
        xT[1 * XS + tid] = pb[NPTS + n] - qv[1];
        xT[2 * XS + tid] = pb[2 * NPTS + n] - qv[2];
    }
    {
        int k = tid & 31, fg = tid >> 5;
        int n = il[k];
        const float* fb = feats + ((size_t)b * NFEAT + fg * 8) * NPTS + n;
#pragma unroll
        for (int u = 0; u < 8; ++u) xT[(3 + fg * 8 + u) * XS + k] = fb[(size_t)u * NPTS];
    }
    __syncthreads();

    const int o = tid & 63, kb = tid >> 6;
    float acc[8];
    // ---- layer 1: 67 -> 64 ----
#pragma unroll
    for (int j = 0; j < 8; ++j) acc[j] = 0.f;
    for (int c = 0; c < 67; ++c) {
        float wv = wl[c * 64 + o];
        const float4* xp = (const float4*)&xT[c * XS + kb * 8];
        float4 a0 = xp[0], a1 = xp[1];
        acc[0] = fmaf(wv, a0.x, acc[0]); acc[1] = fmaf(wv, a0.y, acc[1]);
        acc[2] = fmaf(wv, a0.z, acc[2]); acc[3] = fmaf(wv, a0.w, acc[3]);
        acc[4] = fmaf(wv, a1.x, acc[4]); acc[5] = fmaf(wv, a1.y, acc[5]);
        acc[6] = fmaf(wv, a1.z, acc[6]); acc[7] = fmaf(wv, a1.w, acc[7]);
    }
    {
        float t = bl[o];
#pragma unroll
        for (int j = 0; j < 8; ++j) {
            float y = acc[j] + t;
            y = y > 0.f ? y : 0.2f * y;
            yA[o * XS + kb * 8 + j] = y;
        }
    }
    __syncthreads();
    for (int i = tid; i < 4096; i += 256) wl[i] = wbuf[4352 + i];
    if (tid < 64) bl[tid] = wbuf[8448 + tid];
    __syncthreads();

    // ---- layer 2: 64 -> 64 ----
#pragma unroll
    for (int j = 0; j < 8; ++j) acc[j] = 0.f;
    for (int c = 0; c < 64; ++c) {
        float wv = wl[c * 64 + o];
        const float4* xp = (const float4*)&yA[c * XS + kb * 8];
        float4 a0 = xp[0], a1 = xp[1];
        acc[0] = fmaf(wv, a0.x, acc[0]); acc[1] = fmaf(wv, a0.y, acc[1]);
        acc[2] = fmaf(wv, a0.z, acc[2]); acc[3] = fmaf(wv, a0.w, acc[3]);
        acc[4] = fmaf(wv, a1.x, acc[4]); acc[5] = fmaf(wv, a1.y, acc[5]);
        acc[6] = fmaf(wv, a1.z, acc[6]); acc[7] = fmaf(wv, a1.w, acc[7]);
    }
    {
        float t = bl[o];
#pragma unroll
        for (int j = 0; j < 8; ++j) {
            float y = acc[j] + t;
            y = y > 0.f ? y : 0.2f * y;
            xT[o * XS + kb * 8 + j] = y;   // y2 into xT (xT reads all done)
        }
    }
    __syncthreads();
    for (int i = tid; i < 8192; i += 256) wl[i] = wbuf[8512 + i];
    if (tid < 128) bl[tid] = wbuf[16704 + tid];
    __syncthreads();

    // ---- layer 3: 64 -> 128, fused max over k ----
    const int o3 = tid & 127, kb3 = tid >> 7;
    float a3[16];
#pragma unroll
    for (int j = 0; j < 16; ++j) a3[j] = 0.f;
    for (int c = 0; c < 64; ++c) {
        float wv = wl[c * 128 + o3];
        const float4* xp = (const float4*)&xT[c * XS + kb3 * 16];
        float4 x0 = xp[0], x1 = xp[1], x2 = xp[2], x3 = xp[3];
        a3[0]  = fmaf(wv, x0.x, a3[0]);  a3[1]  = fmaf(wv, x0.y, a3[1]);
        a3[2]  = fmaf(wv, x0.z, a3[2]);  a3[3]  = fmaf(wv, x0.w, a3[3]);
        a3[4]  = fmaf(wv, x1.x, a3[4]);  a3[5]  = fmaf(wv, x1.y, a3[5]);
        a3[6]  = fmaf(wv, x1.z, a3[6]);  a3[7]  = fmaf(wv, x1.w, a3[7]);
        a3[8]  = fmaf(wv, x2.x, a3[8]);  a3[9]  = fmaf(wv, x2.y, a3[9]);
        a3[10] = fmaf(wv, x2.z, a3[10]); a3[11] = fmaf(wv, x2.w, a3[11]);
        a3[12] = fmaf(wv, x3.x, a3[12]); a3[13] = fmaf(wv, x3.y, a3[13]);
        a3[14] = fmaf(wv, x3.z, a3[14]); a3[15] = fmaf(wv, x3.w, a3[15]);
    }
    {
        float t = bl[o3];
        float m = -3.4e38f;
#pragma unroll
        for (int j = 0; j < 16; ++j) {
            float y = a3[j] + t;
            y = y > 0.f ? y : 0.2f * y;
            m = fmaxf(m, y);
        }
        yA[o3 * 2 + kb3] = m;
    }
    __syncthreads();
    if (tid < 128) {
        float r = fmaxf(yA[tid * 2], yA[tid * 2 + 1]);
        out[((size_t)b * 128 + tid) * NPOINT + q] = r;
    }
}

// ---------------------------------------------------------------------------
extern "C" void kernel_launch(void* const* d_in, const int* in_sizes, int n_in,
                              void* d_out, int out_size, void* d_ws, size_t ws_size,
                              hipStream_t stream) {
    (void)in_sizes; (void)n_in; (void)out_size; (void)ws_size;
    const float* feats  = (const float*)d_in[0];
    const float* points = (const float*)d_in[1];
    const float* w1  = (const float*)d_in[2];
    const float* b1  = (const float*)d_in[3];
    const float* g1  = (const float*)d_in[4];
    const float* bb1 = (const float*)d_in[5];
    const float* m1  = (const float*)d_in[6];
    const float* v1  = (const float*)d_in[7];
    const float* w2  = (const float*)d_in[8];
    const float* b2  = (const float*)d_in[9];
    const float* g2  = (const float*)d_in[10];
    const float* bb2 = (const float*)d_in[11];
    const float* m2  = (const float*)d_in[12];
    const float* v2  = (const float*)d_in[13];
    const float* w3  = (const float*)d_in[14];
    const float* b3  = (const float*)d_in[15];
    const float* g3  = (const float*)d_in[16];
    const float* bb3 = (const float*)d_in[17];
    const float* m3  = (const float*)d_in[18];
    const float* v3  = (const float*)d_in[19];

    float* out = (float*)d_out;
    char*  ws  = (char*)d_ws;
    int*   fidx    = (int*)ws;                           // 8*2048 int = 64 KB
    int*   ballidx = (int*)(ws + 65536);                 // 8*2048*32 int = 2 MB
    float* wbuf    = (float*)(ws + 65536 + 2097152);     // 16832 floats
    float* out_xyz = out + (size_t)NBATCH * 128 * NPOINT;

    hipLaunchKernelGGL(prep_kernel, dim3(66), dim3(256), 0, stream,
                       w1, b1, g1, bb1, m1, v1, w2, b2, g2, bb2, m2, v2,
                       w3, b3, g3, bb3, m3, v3, wbuf);
    hipLaunchKernelGGL(fps_kernel, dim3(NBATCH), dim3(512), 0, stream, points, fidx);
    hipLaunchKernelGGL(bq_kernel, dim3(16384 / 4), dim3(256), 0, stream,
                       points, fidx, ballidx, out_xyz);
    hipLaunchKernelGGL(mlp_kernel, dim3(NBATCH * NPOINT), dim3(256), 0, stream,
                       feats, points, fidx, ballidx, wbuf, out);
}